// Round 1
// baseline (553.042 us; speedup 1.0000x reference)
//
#include <hip/hip_runtime.h>
#include <hip/hip_cooperative_groups.h>

namespace cg = cooperative_groups;

// Linear state-space scan:  x_{k+1} = A x_k + B u_k ; outputs X_k (pre-step
// state) and y_k = C x_k + D u_k (normalized in, denormalized out).
// N=16384 steps, R=256 columns, NX=8, NU=NY=2.
//
// FUSED cooperative kernel (512 blocks x 256 threads, 3 grid.sync()):
//   powers:  every block squares A in LDS -> A^32, A^256 (8 tiny matmuls)
//   phase A: normalize u -> 64KB LDS (kept for replay); zero-state 32-step
//            response d32[c] for 512 fine chunks
//   phase B: blocks 0..63: d256[m] = Horner_{A32}(d32[8m..8m+7])
//   phase C: block 0: serial scan of 64 super-chunks, depth-8 reg prefetch
//   phase D: all blocks: start = s256[c>>3] advanced (c&7) fine chunks
//            (all-upfront prefetched d32 loads), replay 32 steps from LDS u,
//            nt-store X and denormalized Y  -> pure store stream, no u re-read
// Fallback: previous verified 5-kernel pipeline if cooperative launch fails.

#define NSTEPS 16384
#define NUI 2
#define RB 256
#define NXS 8
#define NYO 2
#define LF 32
#define NC1 (NSTEPS / LF)   // 512 fine chunks (32 steps each)
#define NC2 (NC1 / 4)       // 128 (fallback path: 128-step super-chunks)
#define NSUP 8              // fine chunks per super-chunk (fused path)
#define NC2B (NC1 / NSUP)   // 64 super-chunks of 256 steps (fused path)

// ================================================================ fused
__global__ __launch_bounds__(RB, 2) void fused_k(
    const float* __restrict__ u, const float* __restrict__ x0,
    const float* __restrict__ A, const float* __restrict__ Bu,
    const float* __restrict__ Cy, const float* __restrict__ Dyu,
    const float* __restrict__ um, const float* __restrict__ us,
    const float* __restrict__ ym, const float* __restrict__ ys,
    float* __restrict__ Y, float* __restrict__ X,
    float* __restrict__ d32, float* __restrict__ d256,
    float* __restrict__ s256) {
    __shared__ float uL[LF][NUI][RB];   // 64 KB normalized u (this block's chunk)
    __shared__ float Ms[64];            // A-power scratch
    __shared__ float A32s[64];          // A^32
    __shared__ float A256s[64];         // A^256

    const int c = blockIdx.x;           // fine chunk 0..511
    const int t = threadIdx.x;
    const int r = t;                    // column 0..255
    cg::grid_group grid = cg::this_grid();

    // ---- A powers by repeated squaring (every block, LDS; ~400 cycles) ----
    if (t < 64) Ms[t] = A[t];
    __syncthreads();
    {
        const int pi = t >> 3, pj = t & 7;
        for (int it = 0; it < 8; ++it) {   // A^2..A^256
            float acc = 0.f;
            if (t < 64) {
                #pragma unroll
                for (int k = 0; k < 8; ++k) acc += Ms[pi * 8 + k] * Ms[k * 8 + pj];
            }
            __syncthreads();
            if (t < 64) {
                Ms[t] = acc;
                if (it == 4) A32s[t] = acc;   // A^32 after 5 squarings
            }
            __syncthreads();
        }
        if (t < 64) A256s[t] = Ms[t];          // A^256 after 8 squarings
        __syncthreads();
    }

    // ---- phase A: normalize u -> LDS; zero-state response -> d32 ----
    float a[NXS][NXS];
    #pragma unroll
    for (int i = 0; i < NXS; ++i)
        #pragma unroll
        for (int j = 0; j < NXS; ++j) a[i][j] = A[i * NXS + j];
    float b0[NXS], b1[NXS];
    #pragma unroll
    for (int i = 0; i < NXS; ++i) { b0[i] = Bu[i * NUI]; b1[i] = Bu[i * NUI + 1]; }
    const float um0 = um[0], um1 = um[1];
    const float is0 = 1.0f / us[0], is1 = 1.0f / us[1];
    {
        float tv[NXS];
        #pragma unroll
        for (int i = 0; i < NXS; ++i) tv[i] = 0.f;
        const float* up = u + (size_t)c * LF * NUI * RB + r;
        #pragma unroll 4
        for (int j = 0; j < LF; ++j) {
            const float u0 = (up[0]  - um0) * is0;
            const float u1 = (up[RB] - um1) * is1;
            up += NUI * RB;
            uL[j][0][r] = u0;
            uL[j][1][r] = u1;
            float nt[NXS];
            #pragma unroll
            for (int i = 0; i < NXS; ++i) {
                float acc = fmaf(b0[i], u0, b1[i] * u1);
                #pragma unroll
                for (int k = 0; k < NXS; ++k) acc = fmaf(a[i][k], tv[k], acc);
                nt[i] = acc;
            }
            #pragma unroll
            for (int i = 0; i < NXS; ++i) tv[i] = nt[i];
        }
        float* dp = d32 + (size_t)c * NXS * RB + r;
        #pragma unroll
        for (int i = 0; i < NXS; ++i) dp[i * RB] = tv[i];
    }
    __threadfence();
    grid.sync();

    // ---- phase B (blocks 0..63): d256[m] = Horner_{A32}(d32[8m..8m+7]) ----
    if (c < NC2B) {
        float a32[NXS][NXS];
        #pragma unroll
        for (int i = 0; i < NXS; ++i)
            #pragma unroll
            for (int j = 0; j < NXS; ++j) a32[i][j] = A32s[i * 8 + j];
        float xq[NSUP][NXS];   // all 64 loads in flight -> one latency
        #pragma unroll
        for (int q = 0; q < NSUP; ++q) {
            const float* dq = d32 + (size_t)(NSUP * c + q) * NXS * RB + r;
            #pragma unroll
            for (int i = 0; i < NXS; ++i) xq[q][i] = dq[i * RB];
        }
        float s[NXS];
        #pragma unroll
        for (int i = 0; i < NXS; ++i) s[i] = xq[0][i];
        #pragma unroll
        for (int q = 1; q < NSUP; ++q) {
            float nt[NXS];
            #pragma unroll
            for (int i = 0; i < NXS; ++i) {
                float acc = xq[q][i];
                #pragma unroll
                for (int k = 0; k < NXS; ++k) acc = fmaf(a32[i][k], s[k], acc);
                nt[i] = acc;
            }
            #pragma unroll
            for (int i = 0; i < NXS; ++i) s[i] = nt[i];
        }
        float* o = d256 + (size_t)c * NXS * RB + r;
        #pragma unroll
        for (int i = 0; i < NXS; ++i) o[i * RB] = s[i];
    }
    __threadfence();
    grid.sync();

    // ---- phase C (block 0): serial scan of 64 super-chunks ----
    if (c == 0) {
        float mm[NXS][NXS];
        #pragma unroll
        for (int i = 0; i < NXS; ++i)
            #pragma unroll
            for (int j = 0; j < NXS; ++j) mm[i][j] = A256s[i * 8 + j];
        float s[NXS];
        #pragma unroll
        for (int i = 0; i < NXS; ++i) s[i] = x0[i * RB + r];
        float P[8][NXS];   // rotating depth-8 prefetch
        #pragma unroll
        for (int sl = 0; sl < 8; ++sl) {
            const float* dp = d256 + (size_t)sl * NXS * RB + r;
            #pragma unroll
            for (int i = 0; i < NXS; ++i) P[sl][i] = dp[i * RB];
        }
        for (int cc = 0; cc < NC2B; cc += 8) {
            #pragma unroll
            for (int sl = 0; sl < 8; ++sl) {
                const int q = cc + sl;
                float* sp = s256 + (size_t)q * NXS * RB + r;
                #pragma unroll
                for (int i = 0; i < NXS; ++i) sp[i * RB] = s[i];
                float ns[NXS];
                #pragma unroll
                for (int i = 0; i < NXS; ++i) {
                    float acc = P[sl][i];
                    #pragma unroll
                    for (int k = 0; k < NXS; ++k) acc = fmaf(mm[i][k], s[k], acc);
                    ns[i] = acc;
                }
                if (q + 8 < NC2B) {
                    const float* dp = d256 + (size_t)(q + 8) * NXS * RB + r;
                    #pragma unroll
                    for (int i = 0; i < NXS; ++i) P[sl][i] = dp[i * RB];
                }
                #pragma unroll
                for (int i = 0; i < NXS; ++i) s[i] = ns[i];
            }
        }
    }
    __threadfence();
    grid.sync();

    // ---- phase D: advance start, replay 32 steps from LDS u, nt-store ----
    {
        const int m = c >> 3;
        const int p = c & 7;   // block-uniform
        float tv[NXS];
        {
            const float* sp = s256 + (size_t)m * NXS * RB + r;
            #pragma unroll
            for (int i = 0; i < NXS; ++i) tv[i] = sp[i * RB];
        }
        if (p) {
            float a32[NXS][NXS];
            #pragma unroll
            for (int i = 0; i < NXS; ++i)
                #pragma unroll
                for (int j = 0; j < NXS; ++j) a32[i][j] = A32s[i * 8 + j];
            // all d32 operands prefetched upfront (static indices only)
            float Pq[NSUP - 1][NXS];
            #pragma unroll
            for (int q = 0; q < NSUP - 1; ++q) {
                if (q < p) {
                    const float* dp = d32 + (size_t)(NSUP * m + q) * NXS * RB + r;
                    #pragma unroll
                    for (int i = 0; i < NXS; ++i) Pq[q][i] = dp[i * RB];
                }
            }
            #pragma unroll
            for (int q = 0; q < NSUP - 1; ++q) {
                if (q < p) {
                    float nt[NXS];
                    #pragma unroll
                    for (int i = 0; i < NXS; ++i) {
                        float acc = Pq[q][i];
                        #pragma unroll
                        for (int k = 0; k < NXS; ++k) acc = fmaf(a32[i][k], tv[k], acc);
                        nt[i] = acc;
                    }
                    #pragma unroll
                    for (int i = 0; i < NXS; ++i) tv[i] = nt[i];
                }
            }
        }
        float c0[NXS], c1[NXS];
        #pragma unroll
        for (int k = 0; k < NXS; ++k) { c0[k] = Cy[k]; c1[k] = Cy[NXS + k]; }
        const float d00 = Dyu[0], d01 = Dyu[1], d10 = Dyu[2], d11 = Dyu[3];
        const float ym0 = ym[0], ym1 = ym[1], ys0 = ys[0], ys1 = ys[1];
        float* Xp = X + (size_t)c * LF * NXS * RB + r;
        float* Yp = Y + (size_t)c * LF * NYO * RB + r;
        #pragma unroll 4
        for (int j = 0; j < LF; ++j) {
            const float u0 = uL[j][0][r];
            const float u1 = uL[j][1][r];
            #pragma unroll
            for (int i = 0; i < NXS; ++i)
                __builtin_nontemporal_store(tv[i], Xp + i * RB);
            Xp += NXS * RB;
            float y0 = fmaf(d00, u0, d01 * u1);
            float y1 = fmaf(d10, u0, d11 * u1);
            #pragma unroll
            for (int k = 0; k < NXS; ++k) {
                y0 = fmaf(c0[k], tv[k], y0);
                y1 = fmaf(c1[k], tv[k], y1);
            }
            __builtin_nontemporal_store(fmaf(y0, ys0, ym0), Yp);
            __builtin_nontemporal_store(fmaf(y1, ys1, ym1), Yp + RB);
            Yp += NYO * RB;
            float nt[NXS];
            #pragma unroll
            for (int i = 0; i < NXS; ++i) {
                float acc = fmaf(b0[i], u0, b1[i] * u1);
                #pragma unroll
                for (int k = 0; k < NXS; ++k) acc = fmaf(a[i][k], tv[k], acc);
                nt[i] = acc;
            }
            #pragma unroll
            for (int i = 0; i < NXS; ++i) tv[i] = nt[i];
        }
    }
}

// ======================================================= fallback kernels
// (previous verified 5-kernel pipeline, unchanged)
__global__ void pow_k(const float* __restrict__ A, float* __restrict__ A32,
                      float* __restrict__ A64, float* __restrict__ A96,
                      float* __restrict__ A128) {
    __shared__ float M[64], T32[64];
    const int t = threadIdx.x;
    const int i = t >> 3, j = t & 7;
    M[t] = A[t];
    __syncthreads();
    for (int it = 0; it < 5; ++it) {
        float acc = 0.f;
        #pragma unroll
        for (int k = 0; k < 8; ++k) acc += M[i * 8 + k] * M[k * 8 + j];
        __syncthreads();
        M[t] = acc;
        __syncthreads();
    }
    T32[t] = M[t];
    A32[t] = M[t];
    {
        float acc = 0.f;
        #pragma unroll
        for (int k = 0; k < 8; ++k) acc += M[i * 8 + k] * M[k * 8 + j];
        __syncthreads();
        M[t] = acc;
        __syncthreads();
    }
    A64[t] = M[t];
    float a96 = 0.f, a128 = 0.f;
    #pragma unroll
    for (int k = 0; k < 8; ++k) {
        a96  += M[i * 8 + k] * T32[k * 8 + j];
        a128 += M[i * 8 + k] * M[k * 8 + j];
    }
    A96[t] = a96;
    A128[t] = a128;
}

__global__ __launch_bounds__(RB) void phase1_k(
    const float* __restrict__ u, const float* __restrict__ A,
    const float* __restrict__ Bu, const float* __restrict__ um,
    const float* __restrict__ us, float* __restrict__ d32) {
    const int c = blockIdx.x;
    const int r = threadIdx.x;
    float a[NXS][NXS];
    #pragma unroll
    for (int i = 0; i < NXS; ++i)
        #pragma unroll
        for (int j = 0; j < NXS; ++j) a[i][j] = A[i * NXS + j];
    float b0[NXS], b1[NXS];
    #pragma unroll
    for (int i = 0; i < NXS; ++i) { b0[i] = Bu[i * NUI]; b1[i] = Bu[i * NUI + 1]; }
    const float um0 = um[0], um1 = um[1];
    const float is0 = 1.0f / us[0], is1 = 1.0f / us[1];
    float t[NXS];
    #pragma unroll
    for (int i = 0; i < NXS; ++i) t[i] = 0.f;
    const float* up = u + (size_t)c * LF * NUI * RB + r;
    #pragma unroll 4
    for (int j = 0; j < LF; ++j) {
        const float u0 = (up[0]  - um0) * is0;
        const float u1 = (up[RB] - um1) * is1;
        up += NUI * RB;
        float nt[NXS];
        #pragma unroll
        for (int i = 0; i < NXS; ++i) {
            float acc = fmaf(b0[i], u0, b1[i] * u1);
            #pragma unroll
            for (int k = 0; k < NXS; ++k) acc = fmaf(a[i][k], t[k], acc);
            nt[i] = acc;
        }
        #pragma unroll
        for (int i = 0; i < NXS; ++i) t[i] = nt[i];
    }
    float* dp = d32 + (size_t)c * NXS * RB + r;
    #pragma unroll
    for (int i = 0; i < NXS; ++i) dp[i * RB] = t[i];
}

__global__ __launch_bounds__(RB) void combine4_k(
    const float* __restrict__ d32, const float* __restrict__ A32,
    const float* __restrict__ A64, const float* __restrict__ A96,
    float* __restrict__ d128) {
    const int m = blockIdx.x;
    const int r = threadIdx.x;
    float m32[NXS][NXS], m64[NXS][NXS], m96[NXS][NXS];
    #pragma unroll
    for (int i = 0; i < NXS; ++i)
        #pragma unroll
        for (int j = 0; j < NXS; ++j) {
            m32[i][j] = A32[i * NXS + j];
            m64[i][j] = A64[i * NXS + j];
            m96[i][j] = A96[i * NXS + j];
        }
    const float* p = d32 + (size_t)(4 * m) * NXS * RB + r;
    float x0[NXS], x1[NXS], x2[NXS], x3[NXS];
    #pragma unroll
    for (int i = 0; i < NXS; ++i) {
        x0[i] = p[i * RB];
        x1[i] = p[(size_t)NXS * RB + i * RB];
        x2[i] = p[(size_t)2 * NXS * RB + i * RB];
        x3[i] = p[(size_t)3 * NXS * RB + i * RB];
    }
    float* o = d128 + (size_t)m * NXS * RB + r;
    #pragma unroll
    for (int i = 0; i < NXS; ++i) {
        float acc = x3[i];
        #pragma unroll
        for (int k = 0; k < NXS; ++k) {
            acc = fmaf(m96[i][k], x0[k], acc);
            acc = fmaf(m64[i][k], x1[k], acc);
            acc = fmaf(m32[i][k], x2[k], acc);
        }
        o[i * RB] = acc;
    }
}

__global__ __launch_bounds__(64) void phase2_k(
    const float* __restrict__ x0, const float* __restrict__ A128,
    const float* __restrict__ d128, float* __restrict__ s128) {
    const int r = blockIdx.x * 64 + threadIdx.x;
    float m[NXS][NXS];
    #pragma unroll
    for (int i = 0; i < NXS; ++i)
        #pragma unroll
        for (int j = 0; j < NXS; ++j) m[i][j] = A128[i * NXS + j];
    float s[NXS];
    #pragma unroll
    for (int i = 0; i < NXS; ++i) s[i] = x0[i * RB + r];
    float P[8][NXS];
    #pragma unroll
    for (int sl = 0; sl < 8; ++sl) {
        const float* dp = d128 + (size_t)sl * NXS * RB + r;
        #pragma unroll
        for (int i = 0; i < NXS; ++i) P[sl][i] = dp[i * RB];
    }
    for (int c = 0; c < NC2; c += 8) {
        #pragma unroll
        for (int sl = 0; sl < 8; ++sl) {
            const int cc = c + sl;
            float* sp = s128 + (size_t)cc * NXS * RB + r;
            #pragma unroll
            for (int i = 0; i < NXS; ++i) sp[i * RB] = s[i];
            float ns[NXS];
            #pragma unroll
            for (int i = 0; i < NXS; ++i) {
                float acc = P[sl][i];
                #pragma unroll
                for (int k = 0; k < NXS; ++k) acc = fmaf(m[i][k], s[k], acc);
                ns[i] = acc;
            }
            if (cc + 8 < NC2) {
                const float* dp = d128 + (size_t)(cc + 8) * NXS * RB + r;
                #pragma unroll
                for (int i = 0; i < NXS; ++i) P[sl][i] = dp[i * RB];
            }
            #pragma unroll
            for (int i = 0; i < NXS; ++i) s[i] = ns[i];
        }
    }
}

__global__ __launch_bounds__(RB) void phase3_k(
    const float* __restrict__ u, const float* __restrict__ s128,
    const float* __restrict__ d32, const float* __restrict__ A32,
    const float* __restrict__ A, const float* __restrict__ Bu,
    const float* __restrict__ Cy, const float* __restrict__ Dyu,
    const float* __restrict__ um, const float* __restrict__ us,
    const float* __restrict__ ym, const float* __restrict__ ys,
    float* __restrict__ Y, float* __restrict__ X) {
    const int c = blockIdx.x;
    const int r = threadIdx.x;
    const int m = c >> 2;
    const int p = c & 3;
    float a[NXS][NXS];
    #pragma unroll
    for (int i = 0; i < NXS; ++i)
        #pragma unroll
        for (int j = 0; j < NXS; ++j) a[i][j] = A[i * NXS + j];
    float b0[NXS], b1[NXS], c0[NXS], c1[NXS];
    #pragma unroll
    for (int i = 0; i < NXS; ++i) { b0[i] = Bu[i * NUI]; b1[i] = Bu[i * NUI + 1]; }
    #pragma unroll
    for (int k = 0; k < NXS; ++k) { c0[k] = Cy[k]; c1[k] = Cy[NXS + k]; }
    const float d00 = Dyu[0], d01 = Dyu[1], d10 = Dyu[2], d11 = Dyu[3];
    const float um0 = um[0], um1 = um[1];
    const float is0 = 1.0f / us[0], is1 = 1.0f / us[1];
    const float ym0 = ym[0], ym1 = ym[1], ys0 = ys[0], ys1 = ys[1];

    float t[NXS];
    {
        const float* sp = s128 + (size_t)m * NXS * RB + r;
        #pragma unroll
        for (int i = 0; i < NXS; ++i) t[i] = sp[i * RB];
    }
    if (p) {
        float a32[NXS][NXS];
        #pragma unroll
        for (int i = 0; i < NXS; ++i)
            #pragma unroll
            for (int j = 0; j < NXS; ++j) a32[i][j] = A32[i * NXS + j];
        for (int q = 0; q < p; ++q) {
            const float* dp = d32 + (size_t)(4 * m + q) * NXS * RB + r;
            float nt[NXS];
            #pragma unroll
            for (int i = 0; i < NXS; ++i) {
                float acc = dp[i * RB];
                #pragma unroll
                for (int k = 0; k < NXS; ++k) acc = fmaf(a32[i][k], t[k], acc);
                nt[i] = acc;
            }
            #pragma unroll
            for (int i = 0; i < NXS; ++i) t[i] = nt[i];
        }
    }

    const float* up = u + (size_t)c * LF * NUI * RB + r;
    float* Xp = X + (size_t)c * LF * NXS * RB + r;
    float* Yp = Y + (size_t)c * LF * NYO * RB + r;
    #pragma unroll 4
    for (int j = 0; j < LF; ++j) {
        const float u0 = (up[0]  - um0) * is0;
        const float u1 = (up[RB] - um1) * is1;
        up += NUI * RB;
        #pragma unroll
        for (int i = 0; i < NXS; ++i)
            __builtin_nontemporal_store(t[i], Xp + i * RB);
        Xp += NXS * RB;
        float y0 = fmaf(d00, u0, d01 * u1);
        float y1 = fmaf(d10, u0, d11 * u1);
        #pragma unroll
        for (int k = 0; k < NXS; ++k) {
            y0 = fmaf(c0[k], t[k], y0);
            y1 = fmaf(c1[k], t[k], y1);
        }
        __builtin_nontemporal_store(fmaf(y0, ys0, ym0), Yp);
        __builtin_nontemporal_store(fmaf(y1, ys1, ym1), Yp + RB);
        Yp += NYO * RB;
        float nt[NXS];
        #pragma unroll
        for (int i = 0; i < NXS; ++i) {
            float acc = fmaf(b0[i], u0, b1[i] * u1);
            #pragma unroll
            for (int k = 0; k < NXS; ++k) acc = fmaf(a[i][k], t[k], acc);
            nt[i] = acc;
        }
        #pragma unroll
        for (int i = 0; i < NXS; ++i) t[i] = nt[i];
    }
}

extern "C" void kernel_launch(void* const* d_in, const int* in_sizes, int n_in,
                              void* d_out, int out_size, void* d_ws, size_t ws_size,
                              hipStream_t stream) {
    const float* u   = (const float*)d_in[0];
    const float* x0  = (const float*)d_in[1];
    const float* A   = (const float*)d_in[2];
    const float* Bu  = (const float*)d_in[3];
    const float* Cy  = (const float*)d_in[4];
    const float* Dyu = (const float*)d_in[5];
    const float* um  = (const float*)d_in[6];
    const float* us  = (const float*)d_in[7];
    const float* ym  = (const float*)d_in[8];
    const float* ys  = (const float*)d_in[9];

    float* Y = (float*)d_out;                       // (N, NY, R)
    float* X = Y + (size_t)NSTEPS * NYO * RB;       // (N, NX, R)

    float* ws   = (float*)d_ws;
    float* d32  = ws;                               // NC1*NX*R = 4 MB
    float* dsup = d32 + (size_t)NC1 * NXS * RB;     // d256 (fused) / d128 (fallback)
    float* ssup = dsup + (size_t)NC2 * NXS * RB;    // s256 (fused) / s128 (fallback)
    float* Apow = ssup + (size_t)NC2 * NXS * RB;    // 256 floats (fallback pow_k)

    void* args[] = { (void*)&u,  (void*)&x0, (void*)&A,   (void*)&Bu,
                     (void*)&Cy, (void*)&Dyu,(void*)&um,  (void*)&us,
                     (void*)&ym, (void*)&ys, (void*)&Y,   (void*)&X,
                     (void*)&d32,(void*)&dsup,(void*)&ssup };
    hipError_t err = hipLaunchCooperativeKernel(fused_k, dim3(NC1), dim3(RB),
                                                args, 0, stream);
    if (err != hipSuccess) {
        // previous verified 5-kernel pipeline
        float* A32  = Apow;
        float* A64  = Apow + 64;
        float* A96  = Apow + 128;
        float* A128 = Apow + 192;
        pow_k<<<1, 64, 0, stream>>>(A, A32, A64, A96, A128);
        phase1_k<<<NC1, RB, 0, stream>>>(u, A, Bu, um, us, d32);
        combine4_k<<<NC2, RB, 0, stream>>>(d32, A32, A64, A96, dsup);
        phase2_k<<<4, 64, 0, stream>>>(x0, A128, dsup, ssup);
        phase3_k<<<NC1, RB, 0, stream>>>(u, ssup, d32, A32, A, Bu, Cy, Dyu,
                                         um, us, ym, ys, Y, X);
    }
}

// Round 2
// 236.575 us; speedup vs baseline: 2.3377x; 2.3377x over previous
//
#include <hip/hip_runtime.h>

// Linear state-space scan:  x_{k+1} = A x_k + B u_k ; outputs X_k (pre-step
// state) and y_k = C x_k + D u_k (normalized in, denormalized out).
// N=16384 steps, R=256 columns, NX=8, NU=NY=2.
//
// Blocked parallel linear scan, 4 stream-ordered dispatches (no grid sync —
// measured: cg::grid_group::sync() costs ~100us/sync on MI355X):
//   phase1_k:   zero-state response d32[c] of 512 chunks x 32 steps
//   combine8_k: d256[m] = Horner_{A32}(d32[8m..8m+7])   (64 blocks)
//   phase2_k:   serial scan of 64 super-chunks, 4 blocks x 64 cols,
//               depth-8 register prefetch
//   phase3_k:   start = s256[c>>3] advanced (c&7) fine chunks (depth-2
//               rotating prefetch), replay 32 steps, nt-store X and Y
// A-powers are computed per-block in LDS (8x8 repeated squaring, ~0.3us,
// hidden under global-load latency) — no pow_k dispatch, no extra gap.

#define NSTEPS 16384
#define NUI 2
#define RB 256
#define NXS 8
#define NYO 2
#define LF 32
#define NC1 (NSTEPS / LF)   // 512 fine chunks (32 steps each)
#define NSUP 8              // fine chunks per super-chunk
#define NC2B (NC1 / NSUP)   // 64 super-chunks of 256 steps

// ---------------------------------------------------------------- phase1
__global__ __launch_bounds__(RB) void phase1_k(
    const float* __restrict__ u, const float* __restrict__ A,
    const float* __restrict__ Bu, const float* __restrict__ um,
    const float* __restrict__ us, float* __restrict__ d32) {
    const int c = blockIdx.x;
    const int r = threadIdx.x;
    float a[NXS][NXS];
    #pragma unroll
    for (int i = 0; i < NXS; ++i)
        #pragma unroll
        for (int j = 0; j < NXS; ++j) a[i][j] = A[i * NXS + j];
    float b0[NXS], b1[NXS];
    #pragma unroll
    for (int i = 0; i < NXS; ++i) { b0[i] = Bu[i * NUI]; b1[i] = Bu[i * NUI + 1]; }
    const float um0 = um[0], um1 = um[1];
    const float is0 = 1.0f / us[0], is1 = 1.0f / us[1];
    float t[NXS];
    #pragma unroll
    for (int i = 0; i < NXS; ++i) t[i] = 0.f;
    const float* up = u + (size_t)c * LF * NUI * RB + r;
    #pragma unroll 4
    for (int j = 0; j < LF; ++j) {
        const float u0 = (up[0]  - um0) * is0;
        const float u1 = (up[RB] - um1) * is1;
        up += NUI * RB;
        float nt[NXS];
        #pragma unroll
        for (int i = 0; i < NXS; ++i) {
            float acc = fmaf(b0[i], u0, b1[i] * u1);
            #pragma unroll
            for (int k = 0; k < NXS; ++k) acc = fmaf(a[i][k], t[k], acc);
            nt[i] = acc;
        }
        #pragma unroll
        for (int i = 0; i < NXS; ++i) t[i] = nt[i];
    }
    float* dp = d32 + (size_t)c * NXS * RB + r;
    #pragma unroll
    for (int i = 0; i < NXS; ++i) dp[i * RB] = t[i];
}

// ---------------------------------------------------------------- combine8
// d256[m] = A32^7 d32[8m] + A32^6 d32[8m+1] + ... + d32[8m+7]   (Horner)
// A32 computed in-block by repeated squaring (5 iters, threads 0..63).
__global__ __launch_bounds__(RB) void combine8_k(
    const float* __restrict__ d32, const float* __restrict__ A,
    float* __restrict__ d256) {
    __shared__ float Ms[64];
    __shared__ float A32s[64];
    const int m = blockIdx.x;
    const int t = threadIdx.x;
    const int r = t;

    // issue all 64 global loads first — latency overlaps the A32 computation
    float xq[NSUP][NXS];
    #pragma unroll
    for (int q = 0; q < NSUP; ++q) {
        const float* dq = d32 + (size_t)(NSUP * m + q) * NXS * RB + r;
        #pragma unroll
        for (int i = 0; i < NXS; ++i) xq[q][i] = dq[i * RB];
    }

    if (t < 64) Ms[t] = A[t];
    __syncthreads();
    {
        const int pi = t >> 3, pj = t & 7;
        for (int it = 0; it < 5; ++it) {   // A^2, A^4, A^8, A^16, A^32
            float acc = 0.f;
            if (t < 64) {
                #pragma unroll
                for (int k = 0; k < 8; ++k) acc += Ms[pi * 8 + k] * Ms[k * 8 + pj];
            }
            __syncthreads();
            if (t < 64) Ms[t] = acc;
            __syncthreads();
        }
        if (t < 64) A32s[t] = Ms[t];
        __syncthreads();
    }

    float a32[NXS][NXS];
    #pragma unroll
    for (int i = 0; i < NXS; ++i)
        #pragma unroll
        for (int j = 0; j < NXS; ++j) a32[i][j] = A32s[i * 8 + j];

    float s[NXS];
    #pragma unroll
    for (int i = 0; i < NXS; ++i) s[i] = xq[0][i];
    #pragma unroll
    for (int q = 1; q < NSUP; ++q) {
        float nt[NXS];
        #pragma unroll
        for (int i = 0; i < NXS; ++i) {
            float acc = xq[q][i];
            #pragma unroll
            for (int k = 0; k < NXS; ++k) acc = fmaf(a32[i][k], s[k], acc);
            nt[i] = acc;
        }
        #pragma unroll
        for (int i = 0; i < NXS; ++i) s[i] = nt[i];
    }
    float* o = d256 + (size_t)m * NXS * RB + r;
    #pragma unroll
    for (int i = 0; i < NXS; ++i) o[i * RB] = s[i];
}

// ---------------------------------------------------------------- phase2
// Serial scan: s256[m+1] = A256 s256[m] + d256[m]. 4 blocks x 64 columns,
// depth-8 register prefetch. A256 computed in-block (8 squarings).
__global__ __launch_bounds__(64) void phase2_k(
    const float* __restrict__ x0, const float* __restrict__ A,
    const float* __restrict__ d256, float* __restrict__ s256) {
    __shared__ float Ms[64];
    const int t = threadIdx.x;
    const int r = blockIdx.x * 64 + t;

    // issue x0 + first prefetch slices before the power computation
    float s[NXS];
    #pragma unroll
    for (int i = 0; i < NXS; ++i) s[i] = x0[i * RB + r];
    float P[8][NXS];   // rotating depth-8 prefetch
    #pragma unroll
    for (int sl = 0; sl < 8; ++sl) {
        const float* dp = d256 + (size_t)sl * NXS * RB + r;
        #pragma unroll
        for (int i = 0; i < NXS; ++i) P[sl][i] = dp[i * RB];
    }

    Ms[t] = A[t];
    __syncthreads();
    {
        const int pi = t >> 3, pj = t & 7;
        for (int it = 0; it < 8; ++it) {   // A^2 .. A^256
            float acc = 0.f;
            #pragma unroll
            for (int k = 0; k < 8; ++k) acc += Ms[pi * 8 + k] * Ms[k * 8 + pj];
            __syncthreads();
            Ms[t] = acc;
            __syncthreads();
        }
    }
    float m[NXS][NXS];
    #pragma unroll
    for (int i = 0; i < NXS; ++i)
        #pragma unroll
        for (int j = 0; j < NXS; ++j) m[i][j] = Ms[i * 8 + j];

    for (int c = 0; c < NC2B; c += 8) {
        #pragma unroll
        for (int sl = 0; sl < 8; ++sl) {
            const int cc = c + sl;
            float* sp = s256 + (size_t)cc * NXS * RB + r;
            #pragma unroll
            for (int i = 0; i < NXS; ++i) sp[i * RB] = s[i];
            float ns[NXS];
            #pragma unroll
            for (int i = 0; i < NXS; ++i) {
                float acc = P[sl][i];
                #pragma unroll
                for (int k = 0; k < NXS; ++k) acc = fmaf(m[i][k], s[k], acc);
                ns[i] = acc;
            }
            if (cc + 8 < NC2B) {
                const float* dp = d256 + (size_t)(cc + 8) * NXS * RB + r;
                #pragma unroll
                for (int i = 0; i < NXS; ++i) P[sl][i] = dp[i * RB];
            }
            #pragma unroll
            for (int i = 0; i < NXS; ++i) s[i] = ns[i];
        }
    }
}

// ---------------------------------------------------------------- phase3
// Replay each 32-step chunk from its start; nt-store X and denormalized y.
// start = s256[c>>3] advanced (c&7) fine chunks via A32 (in-block powers),
// depth-2 rotating register prefetch on the d32 slices (static unroll).
__global__ __launch_bounds__(RB) void phase3_k(
    const float* __restrict__ u, const float* __restrict__ s256,
    const float* __restrict__ d32, const float* __restrict__ A,
    const float* __restrict__ Bu, const float* __restrict__ Cy,
    const float* __restrict__ Dyu, const float* __restrict__ um,
    const float* __restrict__ us, const float* __restrict__ ym,
    const float* __restrict__ ys, float* __restrict__ Y,
    float* __restrict__ X) {
    __shared__ float Ms[64];
    __shared__ float A32s[64];
    const int c = blockIdx.x;   // 0..511
    const int t = threadIdx.x;
    const int r = t;
    const int m = c >> 3;
    const int p = c & 7;        // block-uniform

    // issue start-state load first
    float tv[NXS];
    {
        const float* sp = s256 + (size_t)m * NXS * RB + r;
        #pragma unroll
        for (int i = 0; i < NXS; ++i) tv[i] = sp[i * RB];
    }

    // A^32 in LDS (threads 0..63), overlapped with the loads above
    if (t < 64) Ms[t] = A[t];
    __syncthreads();
    {
        const int pi = t >> 3, pj = t & 7;
        for (int it = 0; it < 5; ++it) {
            float acc = 0.f;
            if (t < 64) {
                #pragma unroll
                for (int k = 0; k < 8; ++k) acc += Ms[pi * 8 + k] * Ms[k * 8 + pj];
            }
            __syncthreads();
            if (t < 64) Ms[t] = acc;
            __syncthreads();
        }
        if (t < 64) A32s[t] = Ms[t];
        __syncthreads();
    }

    if (p) {  // advance start by p fine chunks: t = A32 t + d32[8m+q]
        float a32[NXS][NXS];
        #pragma unroll
        for (int i = 0; i < NXS; ++i)
            #pragma unroll
            for (int j = 0; j < NXS; ++j) a32[i][j] = A32s[i * 8 + j];
        // depth-2 rotating prefetch, fully static indices (no scratch)
        float Pa[NXS], Pb[NXS];
        const float* dp0 = d32 + (size_t)(NSUP * m) * NXS * RB + r;
        #pragma unroll
        for (int i = 0; i < NXS; ++i) Pa[i] = dp0[i * RB];
        #pragma unroll
        for (int q = 0; q < NSUP - 1; ++q) {
            if (q < p) {
                if (q + 1 < p) {   // issue next slice while computing this one
                    const float* dn = d32 + (size_t)(NSUP * m + q + 1) * NXS * RB + r;
                    if (q & 1) {
                        #pragma unroll
                        for (int i = 0; i < NXS; ++i) Pa[i] = dn[i * RB];
                    } else {
                        #pragma unroll
                        for (int i = 0; i < NXS; ++i) Pb[i] = dn[i * RB];
                    }
                }
                float nt[NXS];
                #pragma unroll
                for (int i = 0; i < NXS; ++i) {
                    float acc = (q & 1) ? Pb[i] : Pa[i];
                    #pragma unroll
                    for (int k = 0; k < NXS; ++k) acc = fmaf(a32[i][k], tv[k], acc);
                    nt[i] = acc;
                }
                #pragma unroll
                for (int i = 0; i < NXS; ++i) tv[i] = nt[i];
            }
        }
    }

    float a[NXS][NXS];
    #pragma unroll
    for (int i = 0; i < NXS; ++i)
        #pragma unroll
        for (int j = 0; j < NXS; ++j) a[i][j] = A[i * NXS + j];
    float b0[NXS], b1[NXS], c0[NXS], c1[NXS];
    #pragma unroll
    for (int i = 0; i < NXS; ++i) { b0[i] = Bu[i * NUI]; b1[i] = Bu[i * NUI + 1]; }
    #pragma unroll
    for (int k = 0; k < NXS; ++k) { c0[k] = Cy[k]; c1[k] = Cy[NXS + k]; }
    const float d00 = Dyu[0], d01 = Dyu[1], d10 = Dyu[2], d11 = Dyu[3];
    const float um0 = um[0], um1 = um[1];
    const float is0 = 1.0f / us[0], is1 = 1.0f / us[1];
    const float ym0 = ym[0], ym1 = ym[1], ys0 = ys[0], ys1 = ys[1];

    const float* up = u + (size_t)c * LF * NUI * RB + r;
    float* Xp = X + (size_t)c * LF * NXS * RB + r;
    float* Yp = Y + (size_t)c * LF * NYO * RB + r;
    #pragma unroll 4
    for (int j = 0; j < LF; ++j) {
        const float u0 = (up[0]  - um0) * is0;
        const float u1 = (up[RB] - um1) * is1;
        up += NUI * RB;
        #pragma unroll
        for (int i = 0; i < NXS; ++i)
            __builtin_nontemporal_store(tv[i], Xp + i * RB);
        Xp += NXS * RB;
        float y0 = fmaf(d00, u0, d01 * u1);
        float y1 = fmaf(d10, u0, d11 * u1);
        #pragma unroll
        for (int k = 0; k < NXS; ++k) {
            y0 = fmaf(c0[k], tv[k], y0);
            y1 = fmaf(c1[k], tv[k], y1);
        }
        __builtin_nontemporal_store(fmaf(y0, ys0, ym0), Yp);
        __builtin_nontemporal_store(fmaf(y1, ys1, ym1), Yp + RB);
        Yp += NYO * RB;
        float nt[NXS];
        #pragma unroll
        for (int i = 0; i < NXS; ++i) {
            float acc = fmaf(b0[i], u0, b1[i] * u1);
            #pragma unroll
            for (int k = 0; k < NXS; ++k) acc = fmaf(a[i][k], tv[k], acc);
            nt[i] = acc;
        }
        #pragma unroll
        for (int i = 0; i < NXS; ++i) tv[i] = nt[i];
    }
}

extern "C" void kernel_launch(void* const* d_in, const int* in_sizes, int n_in,
                              void* d_out, int out_size, void* d_ws, size_t ws_size,
                              hipStream_t stream) {
    const float* u   = (const float*)d_in[0];
    const float* x0  = (const float*)d_in[1];
    const float* A   = (const float*)d_in[2];
    const float* Bu  = (const float*)d_in[3];
    const float* Cy  = (const float*)d_in[4];
    const float* Dyu = (const float*)d_in[5];
    const float* um  = (const float*)d_in[6];
    const float* us  = (const float*)d_in[7];
    const float* ym  = (const float*)d_in[8];
    const float* ys  = (const float*)d_in[9];

    float* Y = (float*)d_out;                       // (N, NY, R)
    float* X = Y + (size_t)NSTEPS * NYO * RB;       // (N, NX, R)

    float* ws   = (float*)d_ws;
    float* d32  = ws;                               // NC1*NX*R  = 4 MB
    float* d256 = d32 + (size_t)NC1 * NXS * RB;     // NC2B*NX*R = 512 KB
    float* s256 = d256 + (size_t)NC2B * NXS * RB;   // NC2B*NX*R = 512 KB

    phase1_k<<<NC1, RB, 0, stream>>>(u, A, Bu, um, us, d32);
    combine8_k<<<NC2B, RB, 0, stream>>>(d32, A, d256);
    phase2_k<<<4, 64, 0, stream>>>(x0, A, d256, s256);
    phase3_k<<<NC1, RB, 0, stream>>>(u, s256, d32, A, Bu, Cy, Dyu,
                                     um, us, ym, ys, Y, X);
}